// Round 3
// baseline (232.361 us; speedup 1.0000x reference)
//
#include <hip/hip_runtime.h>
#include <math.h>

// PCEN: out = (x / (smooth + eps)^alpha + delta)^r - delta^r
// smooth[0]=x[0]; smooth[t] = (1-S)*smooth[t-1] + S*x[t]
// x: [64,128,4096] fp32 -> 8192 rows of T=4096.
//
// Round-2 lesson: traffic was never the issue (FETCH identical with strided
// or coalesced loads); the 79us came from barrier-serialized phases + the
// LDS transpose on the critical path. This version: ONE ROW PER WAVE,
// zero LDS, zero barriers, perfectly coalesced loads/stores.
//
// Key trick: the EMA multiplier a=0.975 is a compile-time constant, so any
// length-n segment map is y -> a^n*y + B with KNOWN A. In coalesced layout
// e = 256*s + 4*lane + i, the row is 16 sequential sub-chunks of 256 elems;
// lane l owns a contiguous 4-run in each. The affine scan reduces to a scan
// over offsets B only:
//   step k:  B = fmaf(a^(4*2^k), B_up, B)    (constant coefficient, 1 shfl)
// Per-lane exclusive A = a^(4*lane) (exact product of 6 constant factors).
// Sub-chunk totals broadcast via v_readlane (VALU, no DS); 16-fma carry
// chain across sub-chunks. smooth[0]=x[0] boundary handled exactly by
// seeding lane0/s0's first offset with x[0] (the A mismatch only multiplies
// the carry y0 = 0, so it cancels exactly).
// Replay is branch-free: sm_i = a^(i+1)*y_lane + Bi[i] then the pointwise
// PCEN with raw v_log/v_exp/v_sqrt (sm+eps in [1e-6, ~1], safe).

#define T_LEN 4096
#define BLOCK 256
#define NSUB  16   // sub-chunks of 256 elems (64 lanes x 4)

constexpr double dpow(double b, int n) {
    double r = 1.0;
    for (int i = 0; i < n; ++i) r *= b;
    return r;
}

__global__ __launch_bounds__(BLOCK, 4) void pcen_kernel(const float* __restrict__ x,
                                                        float* __restrict__ out) {
    constexpr float A_COEF = 0.975f;   // 1 - S
    constexpr float S_COEF = 0.025f;   // S
    constexpr float ALPHA  = 0.98f;
    constexpr float EPS    = 1e-6f;
    constexpr float DELTA  = 2.0f;
    constexpr float SQRT_DELTA = 1.4142135623730951f;
    // scan-step coefficients a^(4*2^k), k=0..5 (double-folded to float)
    constexpr float CS0 = (float)dpow(0.975, 4);
    constexpr float CS1 = (float)dpow(0.975, 8);
    constexpr float CS2 = (float)dpow(0.975, 16);
    constexpr float CS3 = (float)dpow(0.975, 32);
    constexpr float CS4 = (float)dpow(0.975, 64);
    constexpr float CS5 = (float)dpow(0.975, 128);
    constexpr float A256 = (float)dpow(0.975, 256);  // sub-chunk total A
    constexpr float AP1 = (float)dpow(0.975, 1);
    constexpr float AP2 = (float)dpow(0.975, 2);
    constexpr float AP3 = (float)dpow(0.975, 3);
    constexpr float AP4 = (float)dpow(0.975, 4);

    const int tid  = threadIdx.x;
    const int lane = tid & 63;
    const int wid  = tid >> 6;
    const int row  = blockIdx.x * 4 + wid;   // one row per wave

    const float* __restrict__ xr  = x   + (size_t)row * T_LEN;
    float* __restrict__       orr = out + (size_t)row * T_LEN;

    // per-lane exclusive A within a sub-chunk: a^(4*lane), exact constant product
    float a4l = 1.0f;
    a4l *= (lane & 1)  ? CS0 : 1.0f;
    a4l *= (lane & 2)  ? CS1 : 1.0f;
    a4l *= (lane & 4)  ? CS2 : 1.0f;
    a4l *= (lane & 8)  ? CS3 : 1.0f;
    a4l *= (lane & 16) ? CS4 : 1.0f;
    a4l *= (lane & 32) ? CS5 : 1.0f;

    // ---- load whole row, coalesced: sub-chunk s -> dwords [256s+4l, +4) ----
    float4 xq[NSUB];
#pragma unroll
    for (int s = 0; s < NSUB; ++s)
        xq[s] = *(const float4*)(xr + 256 * s + 4 * lane);

    // ---- per-sub-chunk local offset + wave B-scan (constant-A composition) ----
    float Bs[NSUB];  // inclusive offset scan (lane l = offset of lanes 0..l)
#pragma unroll
    for (int s = 0; s < NSUB; ++s) {
        float b = (s == 0 && lane == 0) ? xq[s].x : S_COEF * xq[s].x;
        b = fmaf(A_COEF, b, S_COEF * xq[s].y);
        b = fmaf(A_COEF, b, S_COEF * xq[s].z);
        b = fmaf(A_COEF, b, S_COEF * xq[s].w);
        float bu;
        bu = __shfl_up(b, 1);  if (lane >= 1)  b = fmaf(CS0, bu, b);
        bu = __shfl_up(b, 2);  if (lane >= 2)  b = fmaf(CS1, bu, b);
        bu = __shfl_up(b, 4);  if (lane >= 4)  b = fmaf(CS2, bu, b);
        bu = __shfl_up(b, 8);  if (lane >= 8)  b = fmaf(CS3, bu, b);
        bu = __shfl_up(b, 16); if (lane >= 16) b = fmaf(CS4, bu, b);
        bu = __shfl_up(b, 32); if (lane >= 32) b = fmaf(CS5, bu, b);
        Bs[s] = b;
    }

    // ---- carry across sub-chunks + replay + pointwise PCEN + store ----
    float y = 0.0f;  // smooth entering current sub-chunk (exact 0 for s=0)
#pragma unroll
    for (int s = 0; s < NSUB; ++s) {
        float bex = __shfl_up(Bs[s], 1);
        if (lane == 0) bex = 0.0f;
        float yl = fmaf(a4l, y, bex);   // smooth entering this lane's 4-run

        // local offsets (recomputed: cheaper than keeping 64 more regs)
        float bi0 = (s == 0 && lane == 0) ? xq[s].x : S_COEF * xq[s].x;
        float bi1 = fmaf(A_COEF, bi0, S_COEF * xq[s].y);
        float bi2 = fmaf(A_COEF, bi1, S_COEF * xq[s].z);
        float bi3 = fmaf(A_COEF, bi2, S_COEF * xq[s].w);

        float sm0 = fmaf(AP1, yl, bi0);
        float sm1 = fmaf(AP2, yl, bi1);
        float sm2 = fmaf(AP3, yl, bi2);
        float sm3 = fmaf(AP4, yl, bi3);

        float4 o;
        {
            float p = __builtin_amdgcn_exp2f(-ALPHA * __builtin_amdgcn_logf(sm0 + EPS));
            o.x = __builtin_amdgcn_sqrtf(fmaf(xq[s].x, p, DELTA)) - SQRT_DELTA;
        }
        {
            float p = __builtin_amdgcn_exp2f(-ALPHA * __builtin_amdgcn_logf(sm1 + EPS));
            o.y = __builtin_amdgcn_sqrtf(fmaf(xq[s].y, p, DELTA)) - SQRT_DELTA;
        }
        {
            float p = __builtin_amdgcn_exp2f(-ALPHA * __builtin_amdgcn_logf(sm2 + EPS));
            o.z = __builtin_amdgcn_sqrtf(fmaf(xq[s].z, p, DELTA)) - SQRT_DELTA;
        }
        {
            float p = __builtin_amdgcn_exp2f(-ALPHA * __builtin_amdgcn_logf(sm3 + EPS));
            o.w = __builtin_amdgcn_sqrtf(fmaf(xq[s].w, p, DELTA)) - SQRT_DELTA;
        }
        *(float4*)(orr + 256 * s + 4 * lane) = o;

        // advance carry: y_{s+1} = a^256 * y_s + Bt_s  (Bt from lane 63, SGPR)
        y = fmaf(A256, y,
                 __uint_as_float(__builtin_amdgcn_readlane(__float_as_uint(Bs[s]), 63)));
    }
}

extern "C" void kernel_launch(void* const* d_in, const int* in_sizes, int n_in,
                              void* d_out, int out_size, void* d_ws, size_t ws_size,
                              hipStream_t stream) {
    const float* x = (const float*)d_in[0];
    float* out = (float*)d_out;
    const int rows = in_sizes[0] / T_LEN;  // 64*128 = 8192
    pcen_kernel<<<rows / 4, BLOCK, 0, stream>>>(x, out);
}

// Round 4
// 222.624 us; speedup vs baseline: 1.0437x; 1.0437x over previous
//
#include <hip/hip_runtime.h>
#include <math.h>

// PCEN: out = (x / (smooth + eps)^alpha + delta)^r - delta^r
// smooth[0]=x[0]; smooth[t] = (1-S)*smooth[t-1] + S*x[t]
// x: [64,128,4096] fp32 -> 8192 rows of T=4096.
//
// ROOFLINE NOTE (rounds 0-3): 268 MB read + 268 MB write = 536 MB must
// cross L2; harness fill kernels demonstrate 6.5-6.8 TB/s on this path ->
// ~81 us floor. Rounds 1-3 (strided / LDS-transpose / wave-per-row) all
// converged to 79-86 us. This version returns to the best-measured
// structure (round 0: BLOCK=1024, PER=4, one block/row, 222.1 us total)
// and trims scan work using the constant-coefficient identity:
// the EMA multiplier a=0.975 is compile-time, so every segment map is
// y -> a^n*y + B with KNOWN A. The affine scan reduces to a B-only scan:
//   step k:  B = fmaf(a^(4*2^k), B_up, B)   (literal coeff, ONE shfl/step)
// Per-lane exclusive A = a^(4*lane) (product of 6 literal factors);
// cross-wave combine keeps only wB[] with literal coefficient a^256.
// smooth[0]=x[0] boundary: seed tid0's first offset with x[0]; the A
// mismatch multiplies the incoming carry, which is exactly 0 for tid0.
// Replay: sm_i = a^(i+1)*y_in + b_i, 4 independent fmas; pointwise PCEN
// via raw v_log/v_exp/v_sqrt (sm+eps in [1e-6, ~1], safe range).

#define T_LEN 4096
#define BLOCK 1024
#define PER   4    // 1024*4 = 4096
#define NWAVE (BLOCK / 64)

constexpr double dpow(double b, int n) {
    double r = 1.0;
    for (int i = 0; i < n; ++i) r *= b;
    return r;
}

__global__ __launch_bounds__(BLOCK) void pcen_kernel(const float* __restrict__ x,
                                                     float* __restrict__ out) {
    constexpr float A_COEF = 0.975f;   // 1 - S
    constexpr float S_COEF = 0.025f;   // S
    constexpr float ALPHA  = 0.98f;
    constexpr float EPS    = 1e-6f;
    constexpr float DELTA  = 2.0f;
    constexpr float SQRT_DELTA = 1.4142135623730951f;
    // B-scan step coefficients a^(4*2^k), k=0..5 (double-folded literals)
    constexpr float CS0 = (float)dpow(0.975, 4);
    constexpr float CS1 = (float)dpow(0.975, 8);
    constexpr float CS2 = (float)dpow(0.975, 16);
    constexpr float CS3 = (float)dpow(0.975, 32);
    constexpr float CS4 = (float)dpow(0.975, 64);
    constexpr float CS5 = (float)dpow(0.975, 128);
    constexpr float A256 = (float)dpow(0.975, 256);  // per-wave total A (64 lanes x 4)
    constexpr float AP1 = (float)dpow(0.975, 1);
    constexpr float AP2 = (float)dpow(0.975, 2);
    constexpr float AP3 = (float)dpow(0.975, 3);

    const int row = blockIdx.x;
    const float* __restrict__ xr  = x   + (size_t)row * T_LEN;
    float* __restrict__       orr = out + (size_t)row * T_LEN;

    const int tid  = threadIdx.x;
    const int lane = tid & 63;
    const int wid  = tid >> 6;
    const int base = tid * PER;

    // ---- coalesced load: one float4 per thread (lane-contiguous) ----
    float4 v = *(const float4*)(xr + base);

    // ---- local offsets (kept for replay) ----
    float b0 = (tid == 0) ? v.x : S_COEF * v.x;
    float b1 = fmaf(A_COEF, b0, S_COEF * v.y);
    float b2 = fmaf(A_COEF, b1, S_COEF * v.z);
    float b3 = fmaf(A_COEF, b2, S_COEF * v.w);

    // ---- wave-level B-only scan (constant coefficients, 1 shfl/step) ----
    float B = b3;
    float bu;
    bu = __shfl_up(B, 1);  if (lane >= 1)  B = fmaf(CS0, bu, B);
    bu = __shfl_up(B, 2);  if (lane >= 2)  B = fmaf(CS1, bu, B);
    bu = __shfl_up(B, 4);  if (lane >= 4)  B = fmaf(CS2, bu, B);
    bu = __shfl_up(B, 8);  if (lane >= 8)  B = fmaf(CS3, bu, B);
    bu = __shfl_up(B, 16); if (lane >= 16) B = fmaf(CS4, bu, B);
    bu = __shfl_up(B, 32); if (lane >= 32) B = fmaf(CS5, bu, B);

    // ---- cross-wave combine: only offsets needed (A per wave = a^256) ----
    __shared__ float wB[NWAVE];
    if (lane == 63) wB[wid] = B;
    __syncthreads();

    // exclusive-within-wave offset
    float Bex = __shfl_up(B, 1);
    if (lane == 0) Bex = 0.0f;

    // exclusive wave prefix (uniform within wave; literal coefficient)
    float WB = 0.0f;
    for (int w = 0; w < wid; ++w) {
        WB = fmaf(A256, WB, wB[w]);
    }

    // per-lane exclusive A within the wave: a^(4*lane), literal product
    float a4l = 1.0f;
    a4l *= (lane & 1)  ? CS0 : 1.0f;
    a4l *= (lane & 2)  ? CS1 : 1.0f;
    a4l *= (lane & 4)  ? CS2 : 1.0f;
    a4l *= (lane & 8)  ? CS3 : 1.0f;
    a4l *= (lane & 16) ? CS4 : 1.0f;
    a4l *= (lane & 32) ? CS5 : 1.0f;

    // smooth entering this thread's 4-run (tid0: exactly 0, maps absorb)
    float y_in = fmaf(a4l, WB, Bex);

    // ---- replay: 4 independent fmas (powers are literals) ----
    float sm0 = fmaf(AP1, y_in, b0);
    float sm1 = fmaf(AP2, y_in, b1);
    float sm2 = fmaf(AP3, y_in, b2);
    float sm3 = fmaf(CS0, y_in, b3);   // a^4

    // ---- pointwise PCEN + coalesced store ----
    float4 o;
    {
        float p = __builtin_amdgcn_exp2f(-ALPHA * __builtin_amdgcn_logf(sm0 + EPS));
        o.x = __builtin_amdgcn_sqrtf(fmaf(v.x, p, DELTA)) - SQRT_DELTA;
    }
    {
        float p = __builtin_amdgcn_exp2f(-ALPHA * __builtin_amdgcn_logf(sm1 + EPS));
        o.y = __builtin_amdgcn_sqrtf(fmaf(v.y, p, DELTA)) - SQRT_DELTA;
    }
    {
        float p = __builtin_amdgcn_exp2f(-ALPHA * __builtin_amdgcn_logf(sm2 + EPS));
        o.z = __builtin_amdgcn_sqrtf(fmaf(v.z, p, DELTA)) - SQRT_DELTA;
    }
    {
        float p = __builtin_amdgcn_exp2f(-ALPHA * __builtin_amdgcn_logf(sm3 + EPS));
        o.w = __builtin_amdgcn_sqrtf(fmaf(v.w, p, DELTA)) - SQRT_DELTA;
    }
    *(float4*)(orr + base) = o;
}

extern "C" void kernel_launch(void* const* d_in, const int* in_sizes, int n_in,
                              void* d_out, int out_size, void* d_ws, size_t ws_size,
                              hipStream_t stream) {
    const float* x = (const float*)d_in[0];
    float* out = (float*)d_out;
    const int rows = in_sizes[0] / T_LEN;  // 64*128 = 8192
    pcen_kernel<<<rows, BLOCK, 0, stream>>>(x, out);
}